// Round 11
// baseline (371.509 us; speedup 1.0000x reference)
//
#include <hip/hip_runtime.h>
#include <hip/hip_bf16.h>
#include <math.h>

#define NDIM 4096
#define CDIM 256
#define KD   32
#define SCALE 0.17677669529663687f   // 1/sqrt(32)
// ALPHA = SCALE * log2(e): folded into Wf so scores are base-2 exponents
#define ALPHA (0.17677669529663687f * 1.44269504088896341f)
#define SHIFT2 11.541560327111707f   // 8 * log2(e)

typedef __attribute__((ext_vector_type(8))) short short8;  // 8 bf16 = 4 VGPRs
typedef __attribute__((ext_vector_type(4))) float f32x4;
typedef unsigned short u16;
typedef unsigned int u32;

__device__ __forceinline__ u32 f2bf(float x) {  // fp32 -> bf16 bits, RNE
  union { float f; u32 u; } v; v.f = x;
  return (v.u + 0x7FFFu + ((v.u >> 16) & 1u)) >> 16;
}

__device__ __forceinline__ u32 pack_bf16x2(float a, float b) {
  __hip_bfloat162 h2 = __float22bfloat162_rn(make_float2(a, b));
  u32 r;
  __builtin_memcpy(&r, &h2, 4);
  return r;
}

// load 8 consecutive fp32 weights, scale, cast to bf16 short8 (RNE, same
// bits as the old cast_all path)
__device__ __forceinline__ short8 load_w8(const float* __restrict__ p,
                                          float scale) {
  float4 v0 = *(const float4*)p;
  float4 v1 = *(const float4*)(p + 4);
  short8 r;
  r[0] = (short)f2bf(v0.x * scale);
  r[1] = (short)f2bf(v0.y * scale);
  r[2] = (short)f2bf(v0.z * scale);
  r[3] = (short)f2bf(v0.w * scale);
  r[4] = (short)f2bf(v1.x * scale);
  r[5] = (short)f2bf(v1.y * scale);
  r[6] = (short)f2bf(v1.z * scale);
  r[7] = (short)f2bf(v1.w * scale);
  return r;
}

#define MFMA16(a, b, c) __builtin_amdgcn_mfma_f32_16x16x32_bf16((a), (b), (c), 0, 0, 0)

// ---------------------------------------------------------------------------
// tfg: transpose+cast x -> xt AND conv f+g, fused per (64-n, bb) block.
// (Frozen from round 9.)
// ---------------------------------------------------------------------------
__global__ __launch_bounds__(256) void tfg_kernel(
    const float* __restrict__ x1, const float* __restrict__ x2,
    const float* __restrict__ fw, const float* __restrict__ fbias,
    const float* __restrict__ gw, const float* __restrict__ gbias,
    u16* __restrict__ xt, u16* __restrict__ ftT, u16* __restrict__ gtT) {
  __shared__ float ts[64][68];
  const int t = threadIdx.x;
  const int bid = blockIdx.x;
  const int bb = bid & 7;               // XCD pin
  const int ntile = (bid >> 3) * 64;
  const float* xb = ((bb >> 2) ? x2 : x1) + (size_t)(bb & 3) * CDIM * NDIM;
  u16* xtb = xt + (size_t)bb * NDIM * CDIM;

  // ---- phase A: transpose+cast, all 4 C-tiles ----
  const int r = t >> 4, c4 = (t & 15) * 4;
  const int n = t >> 2, Cg = (t & 3) * 16;
#pragma unroll
  for (int ct = 0; ct < 4; ct++) {
    const int Ctile = ct * 64;
#pragma unroll
    for (int i = 0; i < 4; i++) {
      float4 v = *(const float4*)&xb[(size_t)(Ctile + r + i * 16) * NDIM + ntile + c4];
      *(float4*)&ts[r + i * 16][c4] = v;
    }
    __syncthreads();
    u32 pk[8];
#pragma unroll
    for (int j = 0; j < 8; j++) {
      u32 lo = f2bf(ts[Cg + 2 * j][n]);
      u32 hi = f2bf(ts[Cg + 2 * j + 1][n]);
      pk[j] = lo | (hi << 16);
    }
    uint4* dst = (uint4*)&xtb[(size_t)(ntile + n) * CDIM + Ctile + Cg];
    dst[0] = make_uint4(pk[0], pk[1], pk[2], pk[3]);
    dst[1] = make_uint4(pk[4], pk[5], pk[6], pk[7]);
    __syncthreads();  // ts reuse + (last iter) xt stores drained before B
  }

  // ---- phase B: conv f+g for these 64 n rows ----
  const int w = t >> 6, l = t & 63, li = l & 15, q = l >> 4;
  f32x4 zero4 = {0.f, 0.f, 0.f, 0.f};
  f32x4 acc[2][2];
  for (int i = 0; i < 2; i++) for (int j = 0; j < 2; j++) acc[i][j] = zero4;
  const int nrow = ntile + w * 16 + li;

  for (int k0 = 0; k0 < CDIM; k0 += 32) {
    short8 bx = *(const short8*)&xtb[(size_t)nrow * CDIM + k0 + q * 8];
    short8 af0 = load_w8(&fw[(size_t)(li) * CDIM + k0 + q * 8], ALPHA);
    short8 af1 = load_w8(&fw[(size_t)(16 + li) * CDIM + k0 + q * 8], ALPHA);
    short8 ag0 = load_w8(&gw[(size_t)(li) * CDIM + k0 + q * 8], 1.0f);
    short8 ag1 = load_w8(&gw[(size_t)(16 + li) * CDIM + k0 + q * 8], 1.0f);
    acc[0][0] = MFMA16(af0, bx, acc[0][0]);
    acc[0][1] = MFMA16(af1, bx, acc[0][1]);
    acc[1][0] = MFMA16(ag0, bx, acc[1][0]);
    acc[1][1] = MFMA16(ag1, bx, acc[1][1]);
  }
  u16* outs[2] = {ftT + (size_t)bb * NDIM * KD, gtT + (size_t)bb * NDIM * KD};
  const float* biases[2] = {fbias, gbias};
  const float bscale[2] = {ALPHA, 1.0f};
#pragma unroll
  for (int fg = 0; fg < 2; fg++) {
#pragma unroll
    for (int os = 0; os < 2; os++) {
      float b0 = biases[fg][os * 16 + q * 4 + 0] * bscale[fg];
      float b1 = biases[fg][os * 16 + q * 4 + 1] * bscale[fg];
      float b2 = biases[fg][os * 16 + q * 4 + 2] * bscale[fg];
      float b3 = biases[fg][os * 16 + q * 4 + 3] * bscale[fg];
      u32 p0 = f2bf(acc[fg][os][0] + b0) | (f2bf(acc[fg][os][1] + b1) << 16);
      u32 p1 = f2bf(acc[fg][os][2] + b2) | (f2bf(acc[fg][os][3] + b3) << 16);
      *(uint2*)&outs[fg][(size_t)nrow * KD + os * 16 + q * 4] = make_uint2(p0, p1);
    }
  }
}

// ---------------------------------------------------------------------------
// sh: stats + conv_h fused per (32-n, bb) block. (Frozen from round 9.)
// ---------------------------------------------------------------------------
__global__ __launch_bounds__(256, 4) void sh_kernel(
    const u16* __restrict__ ft, const u16* __restrict__ gt,
    const float* __restrict__ h1w, const float* __restrict__ h2w,
    const float* __restrict__ b1, const float* __restrict__ b2,
    const u16* __restrict__ xt, u16* __restrict__ outH) {
  __shared__ float zred[32][64];
  __shared__ float Lsh[32];
  const int t = threadIdx.x, w = t >> 6, l = t & 63, li = l & 15, q = l >> 4;
  const int bid = blockIdx.x;
  const int bb = bid & 7;               // XCD pin (matches tfg/apply)
  const int ntile = (bid >> 3) * 32;
  const int branch = bb >> 2;
  const u16* ftb = ft + (size_t)bb * NDIM * KD;
  const u16* gtb = gt + (size_t)bb * NDIM * KD;
  const float* Wb = branch ? h2w : h1w;
  const float* bias = branch ? b2 : b1;
  const u16* xtb = xt + (size_t)bb * NDIM * CDIM;
  u16* ob = outH + (size_t)bb * CDIM * NDIM;
  f32x4 zero4 = {0.f, 0.f, 0.f, 0.f};

  // ---- phase A: stats for rows ntile..ntile+31 ----
  short8 a0 = *(const short8*)&ftb[(size_t)(ntile + li) * KD + q * 8];
  short8 a1 = *(const short8*)&ftb[(size_t)(ntile + 16 + li) * KD + q * 8];
  f32x4 z0 = zero4, z1 = zero4;
#pragma unroll 2
  for (int it = 0; it < 64; it++) {
    int m = (it * 4 + w) * 16;
    short8 bf = *(const short8*)&gtb[(size_t)(m + li) * KD + q * 8];
    f32x4 S0 = MFMA16(a0, bf, zero4);
    f32x4 S1 = MFMA16(a1, bf, zero4);
#pragma unroll
    for (int reg = 0; reg < 4; reg++) {
      z0[reg] += exp2f(S0[reg] - SHIFT2);
      z1[reg] += exp2f(S1[reg] - SHIFT2);
    }
  }
#pragma unroll
  for (int reg = 0; reg < 4; reg++) {
    zred[q * 4 + reg][w * 16 + li] = z0[reg];
    zred[16 + q * 4 + reg][w * 16 + li] = z1[reg];
  }
  __syncthreads();
  {
    const int rr = t >> 3, i8 = t & 7;
    float4 s1 = *(const float4*)&zred[rr][i8 * 8];
    float4 s2 = *(const float4*)&zred[rr][i8 * 8 + 4];
    float sum = s1.x + s1.y + s1.z + s1.w + s2.x + s2.y + s2.z + s2.w;
    sum += __shfl_xor(sum, 1, 8);
    sum += __shfl_xor(sum, 2, 8);
    sum += __shfl_xor(sum, 4, 8);
    if (i8 == 0) Lsh[rr] = SHIFT2 + __log2f(sum);
  }
  __syncthreads();

  // ---- phase B: conv_h (o0 = w*64, 64 channels per wave; n = 32) ----
  const int o0 = w * 64;
  f32x4 acch[4][2];  // [os][ns]
#pragma unroll
  for (int i = 0; i < 4; i++)
#pragma unroll
    for (int j = 0; j < 2; j++) acch[i][j] = zero4;

  for (int k0 = 0; k0 < CDIM; k0 += 32) {
    short8 aw[4];
#pragma unroll
    for (int os = 0; os < 4; os++)
      aw[os] = load_w8(&Wb[(size_t)(o0 + os * 16 + li) * CDIM + k0 + q * 8], 1.0f);
    short8 bx[2];
#pragma unroll
    for (int ns = 0; ns < 2; ns++)
      bx[ns] = *(const short8*)&xtb[(size_t)(ntile + ns * 16 + li) * CDIM + k0 + q * 8];
#pragma unroll
    for (int os = 0; os < 4; os++) {
      acch[os][0] = MFMA16(aw[os], bx[0], acch[os][0]);
      acch[os][1] = MFMA16(aw[os], bx[1], acch[os][1]);
    }
  }
  float bv[4][4];
#pragma unroll
  for (int os = 0; os < 4; os++)
#pragma unroll
    for (int reg = 0; reg < 4; reg++)
      bv[os][reg] = bias[o0 + os * 16 + q * 4 + reg];
#pragma unroll
  for (int ns = 0; ns < 2; ns++) {
    const int nloc = ns * 16 + li;
    const int nn = ntile + nloc;
    const float ex = exp2f(-Lsh[nloc]);
#pragma unroll
    for (int os = 0; os < 4; os++) {
#pragma unroll
      for (int reg = 0; reg < 4; reg++) {
        int c = o0 + os * 16 + q * 4 + reg;
        ob[(size_t)c * NDIM + nn] = (u16)f2bf((acch[os][ns][reg] + bv[os][reg]) * ex);
      }
    }
  }
}

// ---------------------------------------------------------------------------
// apply v18: out[c][m] = gamma * sum_n h'[c,n]*2^{S2[n,m]} + x[c][m]
// v17 post-mortem: WRITE_SIZE 33->117MB = SCRATCH SPILL. Unified VGPR/AGPR
// file on gfx950: acc(64) sits in AGPRs, leaving 128-64 = 64 arch VGPRs
// under (1024,4). v17's afA+afB (64 VGPR) alone blew the budget. Deep
// buffering is unaffordable; revert to v16's envelope.
// v18 = v16 shell (pad 132 = 0-conflict, batched reads + sched_barrier,
// setprio, ah rotation, lgkm-only barrier, XCD pin) + consumer reshape
// done RIGHT this time (v15's geometry, v16's batching, correct pad):
//   8 consumers = 4 c-ranges(64) x 2 m-halves(64). Each bm b128 now feeds
//   4 MFMAs (was 2) -> CU-wide P reads per chunk 256 -> 128 ds_read_b128
//   (LDS floor ~3.1k -> ~1.5k cyc). h' logical traffic 2x (2 waves share
//   each c-range) - L2-resident (R4: vmem non-binding).
// Register budget (arch VGPRs, 64 avail): consumer ah[2][4]=32 + bm[4]=16
// + addr ~12 = ~60 OK; producer af[8]=32 + gfrag 4 + temps ~15 = ~51 OK.
// WATCH: WRITE_SIZE >> 33MB = spill (abort geometry); flat ~130 with clean
// counters = LDS floor not binding -> structure at practical plateau.
// ---------------------------------------------------------------------------
__global__ __launch_bounds__(1024, 4) void apply_kernel(
    const u16* __restrict__ ft, const u16* __restrict__ gt,
    const u16* __restrict__ h,
    const float* __restrict__ x1, const float* __restrict__ x2,
    const float* __restrict__ gamma1, const float* __restrict__ gamma2,
    float* __restrict__ out) {
  __shared__ u16 Pt[2][128][132];  // [buf][m][n128+pad], 264B row stride
  const int t = threadIdx.x, w = t >> 6, l = t & 63, li = l & 15, q = l >> 4;
  const int bid = blockIdx.x;
  const int bb = bid & 7;             // XCD pin (h'/ft/gt L2-resident)
  const int mtile = (bid >> 3) * 128;
  const int br = bb >> 2, b = bb & 3;
  const u16* ftb = ft + (size_t)bb * NDIM * KD;
  const u16* gtb = gt + (size_t)bb * NDIM * KD;
  const u16* hb = h + (size_t)bb * CDIM * NDIM;
  const float* xb = (br ? x2 : x1) + (size_t)b * CDIM * NDIM;
  const float gmv = br ? gamma2[0] : gamma1[0];
  float* ob = out + (size_t)bb * CDIM * NDIM;

  const bool producer = (w & 1) == 0;
  const int pidx = w >> 1;             // producer: m-subtile 0..7
  const int cidx = w >> 1;             // consumer index 0..7
  const int mbase = (cidx >> 2) * 64;  // consumer: m-half within 128-m tile
  const int c0 = (cidx & 3) * 64;      // consumer: 64-channel range
  f32x4 zero4 = {0.f, 0.f, 0.f, 0.f};

  short8 gfrag;
  if (producer)
    gfrag = *(const short8*)&gtb[(size_t)(mtile + pidx * 16 + li) * KD + q * 8];

  f32x4 acc[4][4];  // [ms][cs] : D[m=mtile+mbase+ms*16+q*4+reg][c=c0+cs*16+li]
#pragma unroll
  for (int i = 0; i < 4; i++)
#pragma unroll
    for (int j = 0; j < 4; j++) acc[i][j] = zero4;

  for (int i = 0; i <= 32; i++) {
    if (producer) {
      if (i < 32) {
        const int n0 = i * 128, buf = i & 1;
        short8 af[8];
#pragma unroll
        for (int j = 0; j < 8; j++)
          af[j] = *(const short8*)&ftb[(size_t)(n0 + j * 16 + li) * KD + q * 8];
#pragma unroll
        for (int j = 0; j < 8; j++) {
          f32x4 S = MFMA16(af[j], gfrag, zero4);
          u32 p0 = pack_bf16x2(exp2f(S[0]), exp2f(S[1]));
          u32 p1 = pack_bf16x2(exp2f(S[2]), exp2f(S[3]));
          // P[m = mtile+pidx*16+li][n = j*16+q*4 .. +3] = 2^{S2[n,m]}
          *(uint2*)&Pt[buf][pidx * 16 + li][j * 16 + q * 4] = make_uint2(p0, p1);
        }
      }
    } else {
      if (i >= 1) {
        const int n0 = (i - 1) * 128, buf = (i - 1) & 1;
        short8 ah[2][4];  // rotating [kh&1][cs]; static after unroll
#pragma unroll
        for (int cs = 0; cs < 4; cs++)
          ah[0][cs] = *(const short8*)
              &hb[(size_t)(c0 + cs * 16 + li) * NDIM + n0 + q * 8];
        __builtin_amdgcn_s_setprio(1);
#pragma unroll
        for (int kh = 0; kh < 4; kh++) {
          if (kh < 3) {
#pragma unroll
            for (int cs = 0; cs < 4; cs++)
              ah[(kh + 1) & 1][cs] = *(const short8*)
                  &hb[(size_t)(c0 + cs * 16 + li) * NDIM + n0 + (kh + 1) * 32 + q * 8];
          }
          // batched P reads: 4 ds_read_b128, then 16 MFMAs (each bm -> 4)
          short8 bm[4];
#pragma unroll
          for (int ms = 0; ms < 4; ms++)
            bm[ms] = *(const short8*)&Pt[buf][mbase + ms * 16 + li][kh * 32 + q * 8];
          __builtin_amdgcn_sched_barrier(0);  // pin the 4-read batch
#pragma unroll
          for (int ms = 0; ms < 4; ms++) {
            acc[ms][0] = MFMA16(bm[ms], ah[kh & 1][0], acc[ms][0]);
            acc[ms][1] = MFMA16(bm[ms], ah[kh & 1][1], acc[ms][1]);
            acc[ms][2] = MFMA16(bm[ms], ah[kh & 1][2], acc[ms][2]);
            acc[ms][3] = MFMA16(bm[ms], ah[kh & 1][3], acc[ms][3]);
          }
        }
        __builtin_amdgcn_s_setprio(0);
      }
    }
    // LDS-only barrier: publish of P_i visible; consumer reads of the
    // other buffer retired; vmem (af/ah) never drained here.
    asm volatile("s_waitcnt lgkmcnt(0)" ::: "memory");
    __builtin_amdgcn_s_barrier();
  }

  // epilogue: consumers hold the full output; float4 stores (m contiguous)
  if (!producer) {
#pragma unroll
    for (int ms = 0; ms < 4; ms++) {
#pragma unroll
      for (int cs = 0; cs < 4; cs++) {
        int c = c0 + cs * 16 + li;
        int m = mtile + mbase + ms * 16 + q * 4;
        size_t idx = (size_t)c * NDIM + m;
        float4 xv = *(const float4*)&xb[idx];
        float4 o;
        o.x = gmv * acc[ms][cs][0] + xv.x;
        o.y = gmv * acc[ms][cs][1] + xv.y;
        o.z = gmv * acc[ms][cs][2] + xv.z;
        o.w = gmv * acc[ms][cs][3] + xv.w;
        *(float4*)&ob[idx] = o;
      }
    }
  }
}

// ---------------------------------------------------------------------------
extern "C" void kernel_launch(void* const* d_in, const int* in_sizes, int n_in,
                              void* d_out, int out_size, void* d_ws, size_t ws_size,
                              hipStream_t stream) {
  const float* x1 = (const float*)d_in[0];
  const float* x2 = (const float*)d_in[1];
  const float* f_w = (const float*)d_in[2];
  const float* f_b = (const float*)d_in[3];
  const float* g_w = (const float*)d_in[4];
  const float* g_b = (const float*)d_in[5];
  const float* h1_w = (const float*)d_in[6];
  const float* h1_b = (const float*)d_in[7];
  const float* h2_w = (const float*)d_in[8];
  const float* h2_b = (const float*)d_in[9];
  const float* gamma1 = (const float*)d_in[10];
  const float* gamma2 = (const float*)d_in[11];
  float* out = (float*)d_out;

  char* ws = (char*)d_ws;
  u16* xt  = (u16*)(ws);                          // [8][4096][256]  16 MB
  u16* wh  = (u16*)(ws + 16777216);               // [8][256][4096]  16 MB
  u16* ftw = (u16*)(ws + 33554432);               // [8][4096][32]    2 MB
  u16* gtw = (u16*)(ws + 35651584);               // [8][4096][32]    2 MB

  tfg_kernel<<<512, 256, 0, stream>>>(x1, x2, f_w, f_b, g_w, g_b,
                                      xt, ftw, gtw);

  sh_kernel<<<1024, 256, 0, stream>>>(ftw, gtw, h1_w, h2_w, h1_b, h2_b,
                                      xt, wh);

  apply_kernel<<<256, 1024, 0, stream>>>(ftw, gtw, wh, x1, x2,
                                         gamma1, gamma2, out);
}

// Round 12
// 300.054 us; speedup vs baseline: 1.2381x; 1.2381x over previous
//
#include <hip/hip_runtime.h>
#include <hip/hip_bf16.h>
#include <math.h>

#define NDIM 4096
#define CDIM 256
#define KD   32
#define SCALE 0.17677669529663687f   // 1/sqrt(32)
// ALPHA = SCALE * log2(e): folded into Wf so scores are base-2 exponents
#define ALPHA (0.17677669529663687f * 1.44269504088896341f)
#define SHIFT2 11.541560327111707f   // 8 * log2(e)

typedef __attribute__((ext_vector_type(8))) short short8;  // 8 bf16 = 4 VGPRs
typedef __attribute__((ext_vector_type(4))) float f32x4;
typedef unsigned short u16;
typedef unsigned int u32;

__device__ __forceinline__ u32 f2bf(float x) {  // fp32 -> bf16 bits, RNE
  union { float f; u32 u; } v; v.f = x;
  return (v.u + 0x7FFFu + ((v.u >> 16) & 1u)) >> 16;
}

__device__ __forceinline__ u32 pack_bf16x2(float a, float b) {
  __hip_bfloat162 h2 = __float22bfloat162_rn(make_float2(a, b));
  u32 r;
  __builtin_memcpy(&r, &h2, 4);
  return r;
}

// load 8 consecutive fp32 weights, scale, cast to bf16 short8 (RNE, same
// bits as the old cast_all path)
__device__ __forceinline__ short8 load_w8(const float* __restrict__ p,
                                          float scale) {
  float4 v0 = *(const float4*)p;
  float4 v1 = *(const float4*)(p + 4);
  short8 r;
  r[0] = (short)f2bf(v0.x * scale);
  r[1] = (short)f2bf(v0.y * scale);
  r[2] = (short)f2bf(v0.z * scale);
  r[3] = (short)f2bf(v0.w * scale);
  r[4] = (short)f2bf(v1.x * scale);
  r[5] = (short)f2bf(v1.y * scale);
  r[6] = (short)f2bf(v1.z * scale);
  r[7] = (short)f2bf(v1.w * scale);
  return r;
}

#define MFMA16(a, b, c) __builtin_amdgcn_mfma_f32_16x16x32_bf16((a), (b), (c), 0, 0, 0)

// ---------------------------------------------------------------------------
// tfg: transpose+cast x -> xt AND conv f+g, fused per (64-n, bb) block.
// R12 tweak (only change this round besides the apply revert): phase A also
// stashes the packed bf16 tile in LDS xs[64][264] (132-dword row stride =
// the SAME stride measured at 0 bank conflicts for this read shape in v11's
// Pt). Phase B reads bx from LDS instead of round-tripping through L2.
// Global xt writes kept (sh/apply consume them). LDS 51KB/block.
// ---------------------------------------------------------------------------
__global__ __launch_bounds__(256) void tfg_kernel(
    const float* __restrict__ x1, const float* __restrict__ x2,
    const float* __restrict__ fw, const float* __restrict__ fbias,
    const float* __restrict__ gw, const float* __restrict__ gbias,
    u16* __restrict__ xt, u16* __restrict__ ftT, u16* __restrict__ gtT) {
  __shared__ float ts[64][68];
  __shared__ u16 xs[64][264];  // [n_local][c + pad], 528B row = 132 dwords
  const int t = threadIdx.x;
  const int bid = blockIdx.x;
  const int bb = bid & 7;               // XCD pin
  const int ntile = (bid >> 3) * 64;
  const float* xb = ((bb >> 2) ? x2 : x1) + (size_t)(bb & 3) * CDIM * NDIM;
  u16* xtb = xt + (size_t)bb * NDIM * CDIM;

  // ---- phase A: transpose+cast, all 4 C-tiles ----
  const int r = t >> 4, c4 = (t & 15) * 4;
  const int n = t >> 2, Cg = (t & 3) * 16;
#pragma unroll
  for (int ct = 0; ct < 4; ct++) {
    const int Ctile = ct * 64;
#pragma unroll
    for (int i = 0; i < 4; i++) {
      float4 v = *(const float4*)&xb[(size_t)(Ctile + r + i * 16) * NDIM + ntile + c4];
      *(float4*)&ts[r + i * 16][c4] = v;
    }
    __syncthreads();
    u32 pk[8];
#pragma unroll
    for (int j = 0; j < 8; j++) {
      u32 lo = f2bf(ts[Cg + 2 * j][n]);
      u32 hi = f2bf(ts[Cg + 2 * j + 1][n]);
      pk[j] = lo | (hi << 16);
    }
    uint4* dst = (uint4*)&xtb[(size_t)(ntile + n) * CDIM + Ctile + Cg];
    dst[0] = make_uint4(pk[0], pk[1], pk[2], pk[3]);
    dst[1] = make_uint4(pk[4], pk[5], pk[6], pk[7]);
    uint4* lst = (uint4*)&xs[n][Ctile + Cg];
    lst[0] = make_uint4(pk[0], pk[1], pk[2], pk[3]);
    lst[1] = make_uint4(pk[4], pk[5], pk[6], pk[7]);
    __syncthreads();  // ts reuse; last iter: xs visible before phase B
  }

  // ---- phase B: conv f+g for these 64 n rows (bx from LDS stash) ----
  const int w = t >> 6, l = t & 63, li = l & 15, q = l >> 4;
  f32x4 zero4 = {0.f, 0.f, 0.f, 0.f};
  f32x4 acc[2][2];
  for (int i = 0; i < 2; i++) for (int j = 0; j < 2; j++) acc[i][j] = zero4;
  const int nrow = ntile + w * 16 + li;
  const int nloc = w * 16 + li;

  for (int k0 = 0; k0 < CDIM; k0 += 32) {
    short8 bx = *(const short8*)&xs[nloc][k0 + q * 8];
    short8 af0 = load_w8(&fw[(size_t)(li) * CDIM + k0 + q * 8], ALPHA);
    short8 af1 = load_w8(&fw[(size_t)(16 + li) * CDIM + k0 + q * 8], ALPHA);
    short8 ag0 = load_w8(&gw[(size_t)(li) * CDIM + k0 + q * 8], 1.0f);
    short8 ag1 = load_w8(&gw[(size_t)(16 + li) * CDIM + k0 + q * 8], 1.0f);
    acc[0][0] = MFMA16(af0, bx, acc[0][0]);
    acc[0][1] = MFMA16(af1, bx, acc[0][1]);
    acc[1][0] = MFMA16(ag0, bx, acc[1][0]);
    acc[1][1] = MFMA16(ag1, bx, acc[1][1]);
  }
  u16* outs[2] = {ftT + (size_t)bb * NDIM * KD, gtT + (size_t)bb * NDIM * KD};
  const float* biases[2] = {fbias, gbias};
  const float bscale[2] = {ALPHA, 1.0f};
#pragma unroll
  for (int fg = 0; fg < 2; fg++) {
#pragma unroll
    for (int os = 0; os < 2; os++) {
      float b0 = biases[fg][os * 16 + q * 4 + 0] * bscale[fg];
      float b1 = biases[fg][os * 16 + q * 4 + 1] * bscale[fg];
      float b2 = biases[fg][os * 16 + q * 4 + 2] * bscale[fg];
      float b3 = biases[fg][os * 16 + q * 4 + 3] * bscale[fg];
      u32 p0 = f2bf(acc[fg][os][0] + b0) | (f2bf(acc[fg][os][1] + b1) << 16);
      u32 p1 = f2bf(acc[fg][os][2] + b2) | (f2bf(acc[fg][os][3] + b3) << 16);
      *(uint2*)&outs[fg][(size_t)nrow * KD + os * 16 + q * 4] = make_uint2(p0, p1);
    }
  }
}

// ---------------------------------------------------------------------------
// sh: stats + conv_h fused per (32-n, bb) block. (Frozen from round 9.)
// ---------------------------------------------------------------------------
__global__ __launch_bounds__(256, 4) void sh_kernel(
    const u16* __restrict__ ft, const u16* __restrict__ gt,
    const float* __restrict__ h1w, const float* __restrict__ h2w,
    const float* __restrict__ b1, const float* __restrict__ b2,
    const u16* __restrict__ xt, u16* __restrict__ outH) {
  __shared__ float zred[32][64];
  __shared__ float Lsh[32];
  const int t = threadIdx.x, w = t >> 6, l = t & 63, li = l & 15, q = l >> 4;
  const int bid = blockIdx.x;
  const int bb = bid & 7;               // XCD pin (matches tfg/apply)
  const int ntile = (bid >> 3) * 32;
  const int branch = bb >> 2;
  const u16* ftb = ft + (size_t)bb * NDIM * KD;
  const u16* gtb = gt + (size_t)bb * NDIM * KD;
  const float* Wb = branch ? h2w : h1w;
  const float* bias = branch ? b2 : b1;
  const u16* xtb = xt + (size_t)bb * NDIM * CDIM;
  u16* ob = outH + (size_t)bb * CDIM * NDIM;
  f32x4 zero4 = {0.f, 0.f, 0.f, 0.f};

  // ---- phase A: stats for rows ntile..ntile+31 ----
  short8 a0 = *(const short8*)&ftb[(size_t)(ntile + li) * KD + q * 8];
  short8 a1 = *(const short8*)&ftb[(size_t)(ntile + 16 + li) * KD + q * 8];
  f32x4 z0 = zero4, z1 = zero4;
#pragma unroll 2
  for (int it = 0; it < 64; it++) {
    int m = (it * 4 + w) * 16;
    short8 bf = *(const short8*)&gtb[(size_t)(m + li) * KD + q * 8];
    f32x4 S0 = MFMA16(a0, bf, zero4);
    f32x4 S1 = MFMA16(a1, bf, zero4);
#pragma unroll
    for (int reg = 0; reg < 4; reg++) {
      z0[reg] += exp2f(S0[reg] - SHIFT2);
      z1[reg] += exp2f(S1[reg] - SHIFT2);
    }
  }
#pragma unroll
  for (int reg = 0; reg < 4; reg++) {
    zred[q * 4 + reg][w * 16 + li] = z0[reg];
    zred[16 + q * 4 + reg][w * 16 + li] = z1[reg];
  }
  __syncthreads();
  {
    const int rr = t >> 3, i8 = t & 7;
    float4 s1 = *(const float4*)&zred[rr][i8 * 8];
    float4 s2 = *(const float4*)&zred[rr][i8 * 8 + 4];
    float sum = s1.x + s1.y + s1.z + s1.w + s2.x + s2.y + s2.z + s2.w;
    sum += __shfl_xor(sum, 1, 8);
    sum += __shfl_xor(sum, 2, 8);
    sum += __shfl_xor(sum, 4, 8);
    if (i8 == 0) Lsh[rr] = SHIFT2 + __log2f(sum);
  }
  __syncthreads();

  // ---- phase B: conv_h (o0 = w*64, 64 channels per wave; n = 32) ----
  const int o0 = w * 64;
  f32x4 acch[4][2];  // [os][ns]
#pragma unroll
  for (int i = 0; i < 4; i++)
#pragma unroll
    for (int j = 0; j < 2; j++) acch[i][j] = zero4;

  for (int k0 = 0; k0 < CDIM; k0 += 32) {
    short8 aw[4];
#pragma unroll
    for (int os = 0; os < 4; os++)
      aw[os] = load_w8(&Wb[(size_t)(o0 + os * 16 + li) * CDIM + k0 + q * 8], 1.0f);
    short8 bx[2];
#pragma unroll
    for (int ns = 0; ns < 2; ns++)
      bx[ns] = *(const short8*)&xtb[(size_t)(ntile + ns * 16 + li) * CDIM + k0 + q * 8];
#pragma unroll
    for (int os = 0; os < 4; os++) {
      acch[os][0] = MFMA16(aw[os], bx[0], acch[os][0]);
      acch[os][1] = MFMA16(aw[os], bx[1], acch[os][1]);
    }
  }
  float bv[4][4];
#pragma unroll
  for (int os = 0; os < 4; os++)
#pragma unroll
    for (int reg = 0; reg < 4; reg++)
      bv[os][reg] = bias[o0 + os * 16 + q * 4 + reg];
#pragma unroll
  for (int ns = 0; ns < 2; ns++) {
    const int nloc = ns * 16 + li;
    const int nn = ntile + nloc;
    const float ex = exp2f(-Lsh[nloc]);
#pragma unroll
    for (int os = 0; os < 4; os++) {
#pragma unroll
      for (int reg = 0; reg < 4; reg++) {
        int c = o0 + os * 16 + q * 4 + reg;
        ob[(size_t)c * NDIM + nn] = (u16)f2bf((acch[os][ns][reg] + bv[os][reg]) * ex);
      }
    }
  }
}

// ---------------------------------------------------------------------------
// apply v16 EXACT REVERT (R8/R9 proven: 130.5 us, MfmaUtil 24.7, VGPR 64,
// WRITE 33MB, 0 conflicts). v17 (deep buffer) and v18 (c=64 reshape) both
// spilled: unified VGPR/AGPR file leaves 128-64(acc) = 64 arch VGPRs under
// (1024,4); only this geometry (acc 64 + ah 16 + bm 16 + addr ~12) fits.
// 8P/8C role-split, pad 132, batched ds_reads + sched_barrier, setprio,
// lgkm-only barrier, XCD pin bb=bid&7.
// ---------------------------------------------------------------------------
__global__ __launch_bounds__(1024, 4) void apply_kernel(
    const u16* __restrict__ ft, const u16* __restrict__ gt,
    const u16* __restrict__ h,
    const float* __restrict__ x1, const float* __restrict__ x2,
    const float* __restrict__ gamma1, const float* __restrict__ gamma2,
    float* __restrict__ out) {
  __shared__ u16 Pt[2][128][132];  // [buf][m][n128+pad], 264B row stride
  const int t = threadIdx.x, w = t >> 6, l = t & 63, li = l & 15, q = l >> 4;
  const int bid = blockIdx.x;
  const int bb = bid & 7;             // XCD pin (h'/ft/gt L2-resident)
  const int mtile = (bid >> 3) * 128;
  const int br = bb >> 2, b = bb & 3;
  const u16* ftb = ft + (size_t)bb * NDIM * KD;
  const u16* gtb = gt + (size_t)bb * NDIM * KD;
  const u16* hb = h + (size_t)bb * CDIM * NDIM;
  const float* xb = (br ? x2 : x1) + (size_t)b * CDIM * NDIM;
  const float gmv = br ? gamma2[0] : gamma1[0];
  float* ob = out + (size_t)bb * CDIM * NDIM;

  const bool producer = (w & 1) == 0;
  const int pidx = w >> 1;            // producer: m-subtile 0..7
  const int c0 = (w >> 1) * 32;       // consumer: 32-channel range
  f32x4 zero4 = {0.f, 0.f, 0.f, 0.f};

  short8 gfrag;
  if (producer)
    gfrag = *(const short8*)&gtb[(size_t)(mtile + pidx * 16 + li) * KD + q * 8];

  f32x4 acc[8][2];  // [ms][cs] : D[m=ms*16+q*4+reg][c=c0+cs*16+li]
#pragma unroll
  for (int i = 0; i < 8; i++)
#pragma unroll
    for (int j = 0; j < 2; j++) acc[i][j] = zero4;

  for (int i = 0; i <= 32; i++) {
    if (producer) {
      if (i < 32) {
        const int n0 = i * 128, buf = i & 1;
        short8 af[8];
#pragma unroll
        for (int j = 0; j < 8; j++)
          af[j] = *(const short8*)&ftb[(size_t)(n0 + j * 16 + li) * KD + q * 8];
#pragma unroll
        for (int j = 0; j < 8; j++) {
          f32x4 S = MFMA16(af[j], gfrag, zero4);
          u32 p0 = pack_bf16x2(exp2f(S[0]), exp2f(S[1]));
          u32 p1 = pack_bf16x2(exp2f(S[2]), exp2f(S[3]));
          // P[m = mtile+pidx*16+li][n = j*16+q*4 .. +3] = 2^{S2[n,m]}
          *(uint2*)&Pt[buf][pidx * 16 + li][j * 16 + q * 4] = make_uint2(p0, p1);
        }
      }
    } else {
      if (i >= 1) {
        const int n0 = (i - 1) * 128, buf = (i - 1) & 1;
        short8 ah[2][2];  // rotating [kh&1][cs]; static after unroll
#pragma unroll
        for (int cs = 0; cs < 2; cs++)
          ah[0][cs] = *(const short8*)
              &hb[(size_t)(c0 + cs * 16 + li) * NDIM + n0 + q * 8];
        __builtin_amdgcn_s_setprio(1);
#pragma unroll
        for (int kh = 0; kh < 4; kh++) {
          if (kh < 3) {
#pragma unroll
            for (int cs = 0; cs < 2; cs++)
              ah[(kh + 1) & 1][cs] = *(const short8*)
                  &hb[(size_t)(c0 + cs * 16 + li) * NDIM + n0 + (kh + 1) * 32 + q * 8];
          }
#pragma unroll
          for (int half = 0; half < 2; half++) {
            short8 bm[4];
#pragma unroll
            for (int mi = 0; mi < 4; mi++) {
              const int ms = half * 4 + mi;
              bm[mi] = *(const short8*)&Pt[buf][ms * 16 + li][kh * 32 + q * 8];
            }
            __builtin_amdgcn_sched_barrier(0);  // pin the 4-read batch
#pragma unroll
            for (int mi = 0; mi < 4; mi++) {
              const int ms = half * 4 + mi;
              acc[ms][0] = MFMA16(bm[mi], ah[kh & 1][0], acc[ms][0]);
              acc[ms][1] = MFMA16(bm[mi], ah[kh & 1][1], acc[ms][1]);
            }
          }
        }
        __builtin_amdgcn_s_setprio(0);
      }
    }
    // LDS-only barrier: publish of P_i visible; consumer reads of the
    // other buffer retired; vmem (af/ah) never drained here.
    asm volatile("s_waitcnt lgkmcnt(0)" ::: "memory");
    __builtin_amdgcn_s_barrier();
  }

  // epilogue: consumers hold the full output; float4 stores (m contiguous)
  if (!producer) {
#pragma unroll
    for (int ms = 0; ms < 8; ms++) {
#pragma unroll
      for (int cs = 0; cs < 2; cs++) {
        int c = c0 + cs * 16 + li;
        int m = mtile + ms * 16 + q * 4;
        size_t idx = (size_t)c * NDIM + m;
        float4 xv = *(const float4*)&xb[idx];
        float4 o;
        o.x = gmv * acc[ms][cs][0] + xv.x;
        o.y = gmv * acc[ms][cs][1] + xv.y;
        o.z = gmv * acc[ms][cs][2] + xv.z;
        o.w = gmv * acc[ms][cs][3] + xv.w;
        *(float4*)&ob[idx] = o;
      }
    }
  }
}

// ---------------------------------------------------------------------------
extern "C" void kernel_launch(void* const* d_in, const int* in_sizes, int n_in,
                              void* d_out, int out_size, void* d_ws, size_t ws_size,
                              hipStream_t stream) {
  const float* x1 = (const float*)d_in[0];
  const float* x2 = (const float*)d_in[1];
  const float* f_w = (const float*)d_in[2];
  const float* f_b = (const float*)d_in[3];
  const float* g_w = (const float*)d_in[4];
  const float* g_b = (const float*)d_in[5];
  const float* h1_w = (const float*)d_in[6];
  const float* h1_b = (const float*)d_in[7];
  const float* h2_w = (const float*)d_in[8];
  const float* h2_b = (const float*)d_in[9];
  const float* gamma1 = (const float*)d_in[10];
  const float* gamma2 = (const float*)d_in[11];
  float* out = (float*)d_out;

  char* ws = (char*)d_ws;
  u16* xt  = (u16*)(ws);                          // [8][4096][256]  16 MB
  u16* wh  = (u16*)(ws + 16777216);               // [8][256][4096]  16 MB
  u16* ftw = (u16*)(ws + 33554432);               // [8][4096][32]    2 MB
  u16* gtw = (u16*)(ws + 35651584);               // [8][4096][32]    2 MB

  tfg_kernel<<<512, 256, 0, stream>>>(x1, x2, f_w, f_b, g_w, g_b,
                                      xt, ftw, gtw);

  sh_kernel<<<1024, 256, 0, stream>>>(ftw, gtw, h1_w, h2_w, h1_b, h2_b,
                                      xt, wh);

  apply_kernel<<<256, 1024, 0, stream>>>(ftw, gtw, wh, x1, x2,
                                         gamma1, gamma2, out);
}